// Round 11
// baseline (192.256 us; speedup 1.0000x reference)
//
#include <hip/hip_runtime.h>

// MultiHeadSelfAttention: B=2, S=2048, E=768, H=12, D=64
// R11: producer/consumer wave split (proven in flash, R6: -45%) applied to
//      both GEMMs: 5th wave streams A/B tiles global->VGPR->LDS double-
//      buffered (BK=32); consumer waves carry no vmem so barriers don't
//      drain global latency. Flash/prep = R10 (verified).

typedef __bf16 bf16_t;
typedef bf16_t bf16x8 __attribute__((ext_vector_type(8)));
typedef bf16_t bf16x4 __attribute__((ext_vector_type(4)));
typedef float f32x4 __attribute__((ext_vector_type(4)));
typedef _Float16 f16x4 __attribute__((ext_vector_type(4)));
typedef __fp16 hf2 __attribute__((ext_vector_type(2)));

#define SC2 0.1803368801111137f  // 0.125 * log2(e): qk-scale folded into exp2

__device__ __forceinline__ float bf2f(unsigned short u) {
  union { unsigned int i; float f; } x;
  x.i = ((unsigned int)u) << 16;
  return x.f;
}

__device__ __forceinline__ float fexp2(float x) {
  return __builtin_amdgcn_exp2f(x);  // raw v_exp_f32; args <= 0 here, FTZ exact
}

// dtype probe: wave examines first 1024 u16 words of x. fp32 data => low
// halves carry random mantissa bits => wild bf16 exponents.
__device__ __forceinline__ int detect_bf16_flag(const unsigned short* x) {
  const int lane = threadIdx.x & 63;
  const uint4* p = (const uint4*)x;
  uint4 a = p[lane * 2];
  uint4 b = p[lane * 2 + 1];
  unsigned int w[8] = {a.x, a.y, a.z, a.w, b.x, b.y, b.z, b.w};
  unsigned int big = 0;
#pragma unroll
  for (int i = 0; i < 8; i++) {
    unsigned int e0 = (w[i] >> 7) & 0xFF, e1 = (w[i] >> 23) & 0xFF;
    big |= (e0 > 0x88u) | (e1 > 0x88u);
  }
  unsigned long long bal = __ballot(big != 0u);
  return bal == 0ULL ? 1 : 0;  // 1 => bf16 inputs
}

// ---------------------------------------------------------------- fused prep
__global__ void k_prep(const void* __restrict__ x, const void* __restrict__ mask,
                       const void* __restrict__ Wq, const void* __restrict__ Wk,
                       const void* __restrict__ Wv, const void* __restrict__ Wo,
                       bf16_t* __restrict__ xb, bf16_t* __restrict__ wqkvT,
                       bf16_t* __restrict__ woT, int* __restrict__ mflags) {
  __shared__ float ts[32][33];
  __shared__ int snz;
  const int blk = blockIdx.x;
  const int f = detect_bf16_flag((const unsigned short*)x);

  if (blk < 1536) {  // ---- ingest x (fp32 only; bf16 path reads x directly)
    if (f) return;
    int i = blk * 256 + threadIdx.x;
    const float* xf = (const float*)x + (size_t)i * 8;
    bf16x8 v;
#pragma unroll
    for (int j = 0; j < 8; j++) v[j] = (bf16_t)xf[j];
    *(bf16x8*)(xb + (size_t)i * 8) = v;
  } else if (blk < 3840) {  // ---- W transpose (4 matrices x 24x24 tiles)
    const int t = blk - 1536;
    const int z = t / 576, r = t % 576, kt = r / 24, nt = r % 24;
    const void* wsrc = (z == 0) ? Wq : (z == 1) ? Wk : (z == 2) ? Wv : Wo;
    bf16_t* dst = (z < 3) ? (wqkvT + (size_t)z * 768 * 768) : woT;
    const int c = threadIdx.x & 31, r0 = threadIdx.x >> 5;
#pragma unroll
    for (int i = 0; i < 4; i++) {
      int kr = kt * 32 + r0 + i * 8;
      float v;
      if (f) v = bf2f(((const unsigned short*)wsrc)[(size_t)kr * 768 + nt * 32 + c]);
      else   v = ((const float*)wsrc)[(size_t)kr * 768 + nt * 32 + c];
      ts[r0 + i * 8][c] = v;
    }
    __syncthreads();
#pragma unroll
    for (int i = 0; i < 4; i++) {
      int nr = nt * 32 + r0 + i * 8;
      dst[(size_t)nr * 768 + kt * 32 + c] = (bf16_t)ts[c][r0 + i * 8];
    }
  } else {  // ---- mask nonzero flag per 128x128 tile, uint4 loads
    const int t = blk - 3840;
    const int qt = t >> 4, ktm = t & 15;
    if (threadIdx.x == 0) snz = 0;
    __syncthreads();
    unsigned int nz = 0;
    if (f) {
#pragma unroll
      for (int i = 0; i < 8; i++) {
        int uidx = i * 256 + threadIdx.x;
        int row = uidx >> 4, col = uidx & 15;
        const uint4* p = (const uint4*)((const char*)mask +
            ((size_t)(qt * 128 + row) * 2048 + ktm * 128) * 2 + col * 16);
        uint4 v = *p;
        nz |= ((v.x | v.y | v.z | v.w) & 0x7fff7fffu);
      }
    } else {
#pragma unroll
      for (int i = 0; i < 16; i++) {
        int uidx = i * 256 + threadIdx.x;
        int row = uidx >> 5, col = uidx & 31;
        const uint4* p = (const uint4*)((const char*)mask +
            ((size_t)(qt * 128 + row) * 2048 + ktm * 128) * 4 + col * 16);
        uint4 v = *p;
        nz |= ((v.x | v.y | v.z | v.w) & 0x7fffffffu);
      }
    }
    if (nz) snz = 1;
    __syncthreads();
    if (threadIdx.x == 0) mflags[qt * 16 + ktm] = snz;
  }
}

// ------------------------------------------------------------------ QKV GEMM
// C[4096 x 2304] = A * wqkvT^T, 128x128 tile, 320 thr = 4 consumers (64x64)
// + 1 producer streaming A/B 128x32 tiles double-buffered (BK=32, 24 iters).
// Epilogue: Q,K -> [b,h,s,d] bf16; V -> V^T [b,h,d,s] f16 via LDS transpose.
__global__ __launch_bounds__(320, 4) void k_gemmQKV(
    const bf16_t* __restrict__ xb, const bf16_t* __restrict__ Bm,
    bf16_t* __restrict__ Qd, bf16_t* __restrict__ Kd, _Float16* __restrict__ Vt,
    const unsigned short* __restrict__ xdet) {
  __shared__ __align__(16) char smem[32768];  // A0|A1|B0|B1 8KB each
  _Float16* Tb = (_Float16*)smem;             // V epilogue reuse (17.4KB)

  const int f = detect_bf16_flag(xdet);
  const bf16_t* A = f ? (const bf16_t*)xdet : xb;

  const int tid = threadIdx.x, wid = tid >> 6, lane = tid & 63;
  const int n0 = blockIdx.x * 128, m0 = blockIdx.y * 128;
  const int lr = lane & 15, lk = (lane >> 4) << 3, g4 = (lane >> 4) << 2;

  if (wid == 4) {
    // ---------------- producer: per iter 8 A-loads + 8 B-loads (1KB each)
    const int pr = lane >> 2, pk = (lane & 3) << 3;
    const bf16_t* Ag = A + (size_t)(m0 + pr) * 768 + pk;
    const bf16_t* Bg = Bm + (size_t)(n0 + pr) * 768 + pk;
    const int dst16 = lane * 16;
    uint4 av[8], bv[8];
    // preload k0=0 -> buffer 0
#pragma unroll
    for (int j = 0; j < 8; j++) av[j] = *(const uint4*)(Ag + (size_t)(j * 16) * 768);
#pragma unroll
    for (int j = 0; j < 8; j++) bv[j] = *(const uint4*)(Bg + (size_t)(j * 16) * 768);
#pragma unroll
    for (int j = 0; j < 8; j++) *(uint4*)(smem + j * 1024 + dst16) = av[j];
#pragma unroll
    for (int j = 0; j < 8; j++) *(uint4*)(smem + 16384 + j * 1024 + dst16) = bv[j];
    __syncthreads();  // buf0 ready
    for (int s = 0; s < 24; s++) {
      if (s < 23) {
        const int k0 = (s + 1) * 32;
        char* Ab = smem + ((s + 1) & 1) * 8192;
        char* Bb = smem + 16384 + ((s + 1) & 1) * 8192;
#pragma unroll
        for (int j = 0; j < 8; j++) av[j] = *(const uint4*)(Ag + (size_t)(j * 16) * 768 + k0);
#pragma unroll
        for (int j = 0; j < 8; j++) bv[j] = *(const uint4*)(Bg + (size_t)(j * 16) * 768 + k0);
#pragma unroll
        for (int j = 0; j < 8; j++) *(uint4*)(Ab + j * 1024 + dst16) = av[j];
#pragma unroll
        for (int j = 0; j < 8; j++) *(uint4*)(Bb + j * 1024 + dst16) = bv[j];
      }
      __syncthreads();
    }
    if (n0 < 1536) return;  // Q/K epilogue has no barriers
    // V epilogue: participate in barriers only
#pragma unroll
    for (int half = 0; half < 2; half++) { __syncthreads(); __syncthreads(); }
    return;
  }

  // ---------------- consumer waves (wid 0..3): 64x64 each
  const int wm = (wid >> 1) << 6, wn = (wid & 1) << 6;
  f32x4 acc[4][4];
  const f32x4 z = {0.f, 0.f, 0.f, 0.f};
#pragma unroll
  for (int i = 0; i < 4; i++)
#pragma unroll
    for (int j = 0; j < 4; j++) acc[i][j] = z;

  __syncthreads();  // wait buf0
  for (int s = 0; s < 24; s++) {
    const bf16_t* As = (const bf16_t*)(smem + (s & 1) * 8192);
    const bf16_t* Bs = (const bf16_t*)(smem + 16384 + (s & 1) * 8192);
    bf16x8 af[4], bf_[4];
#pragma unroll
    for (int t = 0; t < 4; t++) af[t]  = *(const bf16x8*)&As[(wm + t * 16 + lr) * 32 + lk];
#pragma unroll
    for (int t = 0; t < 4; t++) bf_[t] = *(const bf16x8*)&Bs[(wn + t * 16 + lr) * 32 + lk];
#pragma unroll
    for (int i = 0; i < 4; i++)
#pragma unroll
      for (int j = 0; j < 4; j++)
        acc[i][j] = __builtin_amdgcn_mfma_f32_16x16x32_bf16(af[i], bf_[j], acc[i][j], 0, 0, 0);
    __syncthreads();
  }

  if (n0 < 1536) {  // Q or K: scatter (16-lane runs contiguous over d)
    bf16_t* dst = (n0 < 768) ? Qd : Kd;
    const int nb = (n0 < 768) ? n0 : n0 - 768;
    const int bb = m0 >> 11;
#pragma unroll
    for (int i = 0; i < 4; i++)
#pragma unroll
      for (int j = 0; j < 4; j++) {
        const int rc = nb + wn + j * 16 + lr;
        const int hh = rc >> 6, dd = rc & 63;
        const size_t base = (((size_t)bb * 12 + hh) * 2048) * 64 + dd;
#pragma unroll
        for (int reg = 0; reg < 4; reg++) {
          const int s = (m0 & 2047) + wm + i * 16 + g4 + reg;
          dst[base + (size_t)s * 64] = (bf16_t)acc[i][j][reg];
        }
      }
  } else {  // V: LDS transpose -> coalesced V^T f16 writes
    const int bb = m0 >> 11;
#pragma unroll
    for (int half = 0; half < 2; half++) {
      if ((wid & 1) == half) {
#pragma unroll
        for (int j = 0; j < 4; j++) {
          const int d_l = j * 16 + lr;
#pragma unroll
          for (int i = 0; i < 4; i++)
#pragma unroll
            for (int reg = 0; reg < 4; reg++)
              Tb[d_l * 136 + wm + i * 16 + g4 + reg] = (_Float16)acc[i][j][reg];
        }
      }
      __syncthreads();
      const int row = tid >> 2, cc = (tid & 3) * 32;
      const int vcol = (n0 - 1536) + half * 64 + row;
      const int hh = vcol >> 6;  // d == row
      _Float16* dstv = Vt + (((size_t)bb * 12 + hh) * 64 + row) * 2048 + (m0 & 2047) + cc;
#pragma unroll
      for (int u = 0; u < 4; u++)
        *(uint4*)(dstv + u * 8) = *(const uint4*)&Tb[row * 136 + cc + u * 8];
      __syncthreads();
    }
  }
}

// ----------------------------------------------------------- flash attention
// R10 structure (verified 58.9us): 768 blocks x 320 thr, 4 consumers +
// producer, double-buffer, ones-MFMA row-sum.
__global__ __launch_bounds__(320, 4) void k_flash(
    const bf16_t* __restrict__ Qd, const bf16_t* __restrict__ Kd,
    const _Float16* __restrict__ Vt, const void* __restrict__ mask,
    const int* __restrict__ mflags, const unsigned short* __restrict__ xdet,
    bf16_t* __restrict__ attn) {
  __shared__ __align__(16) char sm[32768];  // buf p at p*16384: K 8KB | V 8KB

  const int tid = threadIdx.x, wid = tid >> 6, lane = tid & 63;
  const int lr = lane & 15, quad = lane >> 4, lk = quad << 3, g4 = quad << 2;

  const int lin = blockIdx.x;
  const int gx = lin & 7, ww = lin >> 3;
  const int hb = gx * 3 + (ww >> 5);
  const int h = hb % 12, bb = hb / 12;
  const int qt = ww & 31;

  const size_t bh = (size_t)bb * 12 + h;
  const char* Kh = (const char*)(Kd + bh * 2048 * 64);
  const char* Vh = (const char*)(Vt + bh * 64 * 2048);

  if (wid == 4) {
    const char* kS[8]; const char* vS[8];
#pragma unroll
    for (int u = 0; u < 8; u++) {
      const int R = (u >> 1) * 16 + lr;
      const int c = (u & 1) * 4 + quad;
      kS[u] = Kh + R * 128 + c * 16;
      const int u2 = u * 2 + (lane >> 5);
      const int dtv = u2 & 3, ctv = u2 >> 2, j2 = lane & 31;
      vS[u] = Vh + (size_t)(dtv * 16 + (j2 & 15)) * 4096 + ctv * 32 + (j2 >> 4) * 16;
    }
    uint4 kv[8], vv[8];
#pragma unroll
    for (int u = 0; u < 8; u++) kv[u] = *(const uint4*)(kS[u]);
#pragma unroll
    for (int u = 0; u < 8; u++) vv[u] = *(const uint4*)(vS[u]);
#pragma unroll
    for (int u = 0; u < 8; u++) *(uint4*)(sm + u * 1024 + lane * 16) = kv[u];
#pragma unroll
    for (int u = 0; u < 8; u++) *(uint4*)(sm + 8192 + u * 1024 + lane * 16) = vv[u];
    __syncthreads();
    for (int s = 0; s < 32; s++) {
      if (s < 31) {
        const int t = s + 1;
        char* buf = sm + (t & 1) * 16384;
#pragma unroll
        for (int u = 0; u < 8; u++) kv[u] = *(const uint4*)(kS[u] + (size_t)t * 8192);
#pragma unroll
        for (int u = 0; u < 8; u++) vv[u] = *(const uint4*)(vS[u] + (size_t)t * 128);
#pragma unroll
        for (int u = 0; u < 8; u++) *(uint4*)(buf + u * 1024 + lane * 16) = kv[u];
#pragma unroll
        for (int u = 0; u < 8; u++) *(uint4*)(buf + 8192 + u * 1024 + lane * 16) = vv[u];
      }
      __syncthreads();
    }
    return;
  }

  const bf16_t* Qh = Qd + bh * 2048 * 64;
  const int q0 = qt * 64 + wid * 16;
  const int mbf = detect_bf16_flag(xdet);
  const int* mfrow = mflags + (qt >> 1) * 16;
  int mbits = 0;
#pragma unroll
  for (int t = 0; t < 16; t++) mbits |= (mfrow[t] != 0) << t;

  const bf16x8 qf0 = *(const bf16x8*)&Qh[(size_t)(q0 + lr) * 64 + lk];
  const bf16x8 qf1 = *(const bf16x8*)&Qh[(size_t)(q0 + lr) * 64 + 32 + lk];

  f16x4 ones;
  ones[0] = (_Float16)1.f; ones[1] = (_Float16)1.f;
  ones[2] = (_Float16)1.f; ones[3] = (_Float16)1.f;

  const f32x4 z = {0.f, 0.f, 0.f, 0.f};
  f32x4 ot[4];
#pragma unroll
  for (int dt = 0; dt < 4; dt++) ot[dt] = z;
  float mrow = -1e30f, lrow = 0.f;

  __syncthreads();

  for (int s = 0; s < 32; s++) {
    const char* Kc = sm + (s & 1) * 16384;
    const char* Vc = Kc + 8192;

    f32x4 sv[4];
#pragma unroll
    for (int ct = 0; ct < 4; ct++) sv[ct] = z;
#pragma unroll
    for (int ct = 0; ct < 4; ct++) {
      bf16x8 kf0 = *(const bf16x8*)(Kc + ct * 2048 + lane * 16);
      bf16x8 kf1 = *(const bf16x8*)(Kc + ct * 2048 + 1024 + lane * 16);
      sv[ct] = __builtin_amdgcn_mfma_f32_16x16x32_bf16(kf0, qf0, sv[ct], 0, 0, 0);
      sv[ct] = __builtin_amdgcn_mfma_f32_16x16x32_bf16(kf1, qf1, sv[ct], 0, 0, 0);
    }

    if ((mbits >> (s >> 1)) & 1) {
#pragma unroll
      for (int ct = 0; ct < 4; ct++)
#pragma unroll
        for (int reg = 0; reg < 4; reg++) {
          size_t mi = (size_t)(q0 + lr) * 2048 + s * 64 + ct * 16 + g4 + reg;
          float mv = mbf ? bf2f(((const unsigned short*)mask)[mi])
                         : ((const float*)mask)[mi];
          sv[ct][reg] -= 8e9f * mv;
        }
    }

    float t = fmaxf(
        fmaxf(fmaxf(fmaxf(sv[0][0], sv[0][1]), fmaxf(sv[0][2], sv[0][3])),
              fmaxf(fmaxf(sv[1][0], sv[1][1]), fmaxf(sv[1][2], sv[1][3]))),
        fmaxf(fmaxf(fmaxf(sv[2][0], sv[2][1]), fmaxf(sv[2][2], sv[2][3])),
              fmaxf(fmaxf(sv[3][0], sv[3][1]), fmaxf(sv[3][2], sv[3][3]))));
    t = fmaxf(t, __shfl_xor(t, 16));
    t = fmaxf(t, __shfl_xor(t, 32));
    const float mnew = fmaxf(mrow, t);
    if (__ballot(mnew > mrow)) {
      const float alpha = fexp2((mrow - mnew) * SC2);
#pragma unroll
      for (int dt = 0; dt < 4; dt++)
#pragma unroll
        for (int reg = 0; reg < 4; reg++) ot[dt][reg] *= alpha;
      lrow *= alpha;
    }
    mrow = mnew;
    const float mS = mnew * SC2;

    f16x4 pb[4];
#pragma unroll
    for (int ct = 0; ct < 4; ct++) {
      float p0 = fexp2(fmaf(sv[ct][0], SC2, -mS));
      float p1 = fexp2(fmaf(sv[ct][1], SC2, -mS));
      float p2 = fexp2(fmaf(sv[ct][2], SC2, -mS));
      float p3 = fexp2(fmaf(sv[ct][3], SC2, -mS));
      union { hf2 h[2]; f16x4 v; } u;
      u.h[0] = __builtin_amdgcn_cvt_pkrtz(p0, p1);
      u.h[1] = __builtin_amdgcn_cvt_pkrtz(p2, p3);
      pb[ct] = u.v;
    }

    f32x4 asum = z;
#pragma unroll
    for (int ct = 0; ct < 4; ct++) {
      asum = __builtin_amdgcn_mfma_f32_16x16x16f16(ones, pb[ct], asum, 0, 0, 0);
#pragma unroll
      for (int dt = 0; dt < 4; dt++) {
        f16x4 va = *(const f16x4*)(Vc + (ct * 4 + dt) * 512 +
                                   (quad >> 1) * 256 + lr * 16 + (quad & 1) * 8);
        ot[dt] = __builtin_amdgcn_mfma_f32_16x16x16f16(va, pb[ct], ot[dt], 0, 0, 0);
      }
    }
    lrow += asum[0];
    __syncthreads();
  }

  const float inv = 1.0f / lrow;
  bf16_t* arow = attn + ((size_t)bb * 2048 + q0 + lr) * 768 + h * 64 + g4;
#pragma unroll
  for (int dt = 0; dt < 4; dt++) {
    bf16x4 v;
#pragma unroll
    for (int reg = 0; reg < 4; reg++) v[reg] = (bf16_t)(ot[dt][reg] * inv);
    *(bf16x4*)(arow + dt * 16) = v;
  }
}

// -------------------------------------------------- output GEMM (attn @ Wo^T)
// 64x64 tiles -> 768 blocks, 320 thr = 4 consumers (32x32) + 1 producer
// streaming A/B 64x32 tiles double-buffered (BK=32, 24 iters).
__global__ __launch_bounds__(320, 4) void k_gemm2(
    const bf16_t* __restrict__ A, const bf16_t* __restrict__ Bm,
    const void* __restrict__ bo, const unsigned short* __restrict__ xdet,
    float* __restrict__ outF, unsigned short* __restrict__ outH) {
  __shared__ __align__(16) char smem[16384];  // A0|A1|B0|B1 4KB each

  const int tid = threadIdx.x, wid = tid >> 6, lane = tid & 63;
  const int n0 = blockIdx.x * 64, m0 = blockIdx.y * 64;
  const int lr = lane & 15, lk = (lane >> 4) << 3, g4 = (lane >> 4) << 2;

  if (wid == 4) {
    // ---------------- producer: per iter 4 A-loads + 4 B-loads (1KB each)
    const int pr = lane >> 2, pk = (lane & 3) << 3;
    const bf16_t* Ag = A + (size_t)(m0 + pr) * 768 + pk;
    const bf16_t* Bg = Bm + (size_t)(n0 + pr) * 768 + pk;
    const int dst16 = lane * 16;
    uint4 av[4], bv[4];
#pragma unroll
    for (int j = 0; j < 4; j++) av[j] = *(const uint4*)(Ag + (size_t)(j * 16) * 768);
#pragma unroll
    for (int j = 0; j < 4; j++) bv[j] = *(const uint4*)(Bg + (size_t)(j * 16) * 768);
#pragma unroll
    for (int j = 0; j < 4; j++) *(uint4*)(smem + j * 1024 + dst16) = av[j];
#pragma unroll
    for (int j = 0; j < 4; j++) *(uint4*)(smem + 8192 + j * 1024 + dst16) = bv[j];
    __syncthreads();
    for (int s = 0; s < 24; s++) {
      if (s < 23) {
        const int k0 = (s + 1) * 32;
        char* Ab = smem + ((s + 1) & 1) * 4096;
        char* Bb = smem + 8192 + ((s + 1) & 1) * 4096;
#pragma unroll
        for (int j = 0; j < 4; j++) av[j] = *(const uint4*)(Ag + (size_t)(j * 16) * 768 + k0);
#pragma unroll
        for (int j = 0; j < 4; j++) bv[j] = *(const uint4*)(Bg + (size_t)(j * 16) * 768 + k0);
#pragma unroll
        for (int j = 0; j < 4; j++) *(uint4*)(Ab + j * 1024 + dst16) = av[j];
#pragma unroll
        for (int j = 0; j < 4; j++) *(uint4*)(Bb + j * 1024 + dst16) = bv[j];
      }
      __syncthreads();
    }
    return;
  }

  // ---------------- consumer waves (wid 0..3): 32x32 each
  const int wm = (wid >> 1) << 5, wn = (wid & 1) << 5;
  f32x4 acc[2][2];
  const f32x4 z = {0.f, 0.f, 0.f, 0.f};
#pragma unroll
  for (int i = 0; i < 2; i++)
#pragma unroll
    for (int j = 0; j < 2; j++) acc[i][j] = z;

  __syncthreads();
  for (int s = 0; s < 24; s++) {
    const bf16_t* As = (const bf16_t*)(smem + (s & 1) * 4096);
    const bf16_t* Bs = (const bf16_t*)(smem + 8192 + (s & 1) * 4096);
    bf16x8 af[2], bf_[2];
#pragma unroll
    for (int i = 0; i < 2; i++) af[i]  = *(const bf16x8*)&As[(wm + i * 16 + lr) * 32 + lk];
#pragma unroll
    for (int j = 0; j < 2; j++) bf_[j] = *(const bf16x8*)&Bs[(wn + j * 16 + lr) * 32 + lk];
#pragma unroll
    for (int i = 0; i < 2; i++)
#pragma unroll
      for (int j = 0; j < 2; j++)
        acc[i][j] = __builtin_amdgcn_mfma_f32_16x16x32_bf16(af[i], bf_[j], acc[i][j], 0, 0, 0);
    __syncthreads();
  }

  const int obf = detect_bf16_flag(xdet);
#pragma unroll
  for (int i = 0; i < 2; i++)
#pragma unroll
    for (int j = 0; j < 2; j++) {
      const int nn = n0 + wn + j * 16 + lr;
      const float bv = obf ? bf2f(((const unsigned short*)bo)[nn])
                           : ((const float*)bo)[nn];
#pragma unroll
      for (int reg = 0; reg < 4; reg++) {
        const int m = m0 + wm + i * 16 + g4 + reg;
        const float v = acc[i][j][reg] + bv;
        if (obf) outH[(size_t)m * 768 + nn] = __builtin_bit_cast(unsigned short, (bf16_t)v);
        else     outF[(size_t)m * 768 + nn] = v;
      }
    }
}

// -------------------------------------------------------------------- launch
extern "C" void kernel_launch(void* const* d_in, const int* in_sizes, int n_in,
                              void* d_out, int out_size, void* d_ws, size_t ws_size,
                              hipStream_t stream) {
  (void)in_sizes; (void)n_in; (void)out_size; (void)ws_size;
  const void* x    = d_in[0];
  const void* mask = d_in[1];
  const void* Wq   = d_in[2];
  const void* Wk   = d_in[3];
  const void* Wv   = d_in[4];
  const void* Wo   = d_in[5];
  const void* bo   = d_in[6];

  char* w = (char*)d_ws;
  size_t off = 0;
  auto take = [&](size_t b) -> void* {
    void* p = w + off;
    off = (off + b + 255) & ~(size_t)255;
    return p;
  };
  int*      mflags = (int*)take(256 * 4);
  bf16_t*   wqkvT  = (bf16_t*)take((size_t)2304 * 768 * 2);
  bf16_t*   woT    = (bf16_t*)take((size_t)768 * 768 * 2);
  bf16_t*   xb     = (bf16_t*)take((size_t)4096 * 768 * 2);
  bf16_t*   Qd     = (bf16_t*)take((size_t)3145728 * 2);
  bf16_t*   Kd     = (bf16_t*)take((size_t)3145728 * 2);
  _Float16* Vt     = (_Float16*)take((size_t)3145728 * 2);
  bf16_t*   attn   = xb;  // xb dead after QKV GEMM (flash output reuses it)

  k_prep<<<4096, 256, 0, stream>>>(x, mask, Wq, Wk, Wv, Wo, xb, wqkvT, woT, mflags);
  k_gemmQKV<<<dim3(18, 32), 320, 0, stream>>>(xb, wqkvT, Qd, Kd, Vt,
                                              (const unsigned short*)x);
  k_flash<<<768, 320, 0, stream>>>(Qd, Kd, Vt, mask, mflags,
                                   (const unsigned short*)x, attn);
  k_gemm2<<<dim3(12, 64), 320, 0, stream>>>(attn, woT, bo, (const unsigned short*)x,
                                            (float*)d_out, (unsigned short*)d_out);
}

// Round 12
// 178.048 us; speedup vs baseline: 1.0798x; 1.0798x over previous
//
#include <hip/hip_runtime.h>

// MultiHeadSelfAttention: B=2, S=2048, E=768, H=12, D=64
// R12: GEMMs reverted to all-wave glds16 DMA (R10) but restructured to
//      prefetch-before-compute: DMA for tile s+1 issued into the other LDS
//      slot BEFORE consuming tile s, one barrier/iter -> drain overlapped by
//      the ds_read+MFMA phase. Flash/prep = R10 (57.9us verified).

typedef __bf16 bf16_t;
typedef bf16_t bf16x8 __attribute__((ext_vector_type(8)));
typedef bf16_t bf16x4 __attribute__((ext_vector_type(4)));
typedef float f32x4 __attribute__((ext_vector_type(4)));
typedef _Float16 f16x4 __attribute__((ext_vector_type(4)));
typedef __fp16 hf2 __attribute__((ext_vector_type(2)));

#define SC2 0.1803368801111137f  // 0.125 * log2(e): qk-scale folded into exp2

__device__ __forceinline__ float bf2f(unsigned short u) {
  union { unsigned int i; float f; } x;
  x.i = ((unsigned int)u) << 16;
  return x.f;
}

__device__ __forceinline__ float fexp2(float x) {
  return __builtin_amdgcn_exp2f(x);  // raw v_exp_f32; args <= 0 here, FTZ exact
}

__device__ __forceinline__ void glds16(const bf16_t* g, bf16_t* l) {
  __builtin_amdgcn_global_load_lds(
      (const __attribute__((address_space(1))) void*)g,
      (__attribute__((address_space(3))) void*)l, 16, 0, 0);
}

// dtype probe: wave examines first 1024 u16 words of x. fp32 data => low
// halves carry random mantissa bits => wild bf16 exponents.
__device__ __forceinline__ int detect_bf16_flag(const unsigned short* x) {
  const int lane = threadIdx.x & 63;
  const uint4* p = (const uint4*)x;
  uint4 a = p[lane * 2];
  uint4 b = p[lane * 2 + 1];
  unsigned int w[8] = {a.x, a.y, a.z, a.w, b.x, b.y, b.z, b.w};
  unsigned int big = 0;
#pragma unroll
  for (int i = 0; i < 8; i++) {
    unsigned int e0 = (w[i] >> 7) & 0xFF, e1 = (w[i] >> 23) & 0xFF;
    big |= (e0 > 0x88u) | (e1 > 0x88u);
  }
  unsigned long long bal = __ballot(big != 0u);
  return bal == 0ULL ? 1 : 0;  // 1 => bf16 inputs
}

// ---------------------------------------------------------------- fused prep
__global__ void k_prep(const void* __restrict__ x, const void* __restrict__ mask,
                       const void* __restrict__ Wq, const void* __restrict__ Wk,
                       const void* __restrict__ Wv, const void* __restrict__ Wo,
                       bf16_t* __restrict__ xb, bf16_t* __restrict__ wqkvT,
                       bf16_t* __restrict__ woT, int* __restrict__ mflags) {
  __shared__ float ts[32][33];
  __shared__ int snz;
  const int blk = blockIdx.x;
  const int f = detect_bf16_flag((const unsigned short*)x);

  if (blk < 1536) {  // ---- ingest x (fp32 only; bf16 path reads x directly)
    if (f) return;
    int i = blk * 256 + threadIdx.x;
    const float* xf = (const float*)x + (size_t)i * 8;
    bf16x8 v;
#pragma unroll
    for (int j = 0; j < 8; j++) v[j] = (bf16_t)xf[j];
    *(bf16x8*)(xb + (size_t)i * 8) = v;
  } else if (blk < 3840) {  // ---- W transpose (4 matrices x 24x24 tiles)
    const int t = blk - 1536;
    const int z = t / 576, r = t % 576, kt = r / 24, nt = r % 24;
    const void* wsrc = (z == 0) ? Wq : (z == 1) ? Wk : (z == 2) ? Wv : Wo;
    bf16_t* dst = (z < 3) ? (wqkvT + (size_t)z * 768 * 768) : woT;
    const int c = threadIdx.x & 31, r0 = threadIdx.x >> 5;
#pragma unroll
    for (int i = 0; i < 4; i++) {
      int kr = kt * 32 + r0 + i * 8;
      float v;
      if (f) v = bf2f(((const unsigned short*)wsrc)[(size_t)kr * 768 + nt * 32 + c]);
      else   v = ((const float*)wsrc)[(size_t)kr * 768 + nt * 32 + c];
      ts[r0 + i * 8][c] = v;
    }
    __syncthreads();
#pragma unroll
    for (int i = 0; i < 4; i++) {
      int nr = nt * 32 + r0 + i * 8;
      dst[(size_t)nr * 768 + kt * 32 + c] = (bf16_t)ts[c][r0 + i * 8];
    }
  } else {  // ---- mask nonzero flag per 128x128 tile, uint4 loads
    const int t = blk - 3840;
    const int qt = t >> 4, ktm = t & 15;
    if (threadIdx.x == 0) snz = 0;
    __syncthreads();
    unsigned int nz = 0;
    if (f) {
#pragma unroll
      for (int i = 0; i < 8; i++) {
        int uidx = i * 256 + threadIdx.x;
        int row = uidx >> 4, col = uidx & 15;
        const uint4* p = (const uint4*)((const char*)mask +
            ((size_t)(qt * 128 + row) * 2048 + ktm * 128) * 2 + col * 16);
        uint4 v = *p;
        nz |= ((v.x | v.y | v.z | v.w) & 0x7fff7fffu);
      }
    } else {
#pragma unroll
      for (int i = 0; i < 16; i++) {
        int uidx = i * 256 + threadIdx.x;
        int row = uidx >> 5, col = uidx & 31;
        const uint4* p = (const uint4*)((const char*)mask +
            ((size_t)(qt * 128 + row) * 2048 + ktm * 128) * 4 + col * 16);
        uint4 v = *p;
        nz |= ((v.x | v.y | v.z | v.w) & 0x7fffffffu);
      }
    }
    if (nz) snz = 1;
    __syncthreads();
    if (threadIdx.x == 0) mflags[qt * 16 + ktm] = snz;
  }
}

// ------------------------------------------------------------------ QKV GEMM
// C[4096 x 2304] = A * wqkvT^T, 128x128 tile, BK=32 double-buffered with
// prefetch-before-compute: DMA s+1 -> other slot, then consume slot s,
// then one barrier (drain overlapped by compute).
__global__ __launch_bounds__(256, 3) void k_gemmQKV(
    const bf16_t* __restrict__ xb, const bf16_t* __restrict__ Bm,
    bf16_t* __restrict__ Qd, bf16_t* __restrict__ Kd, _Float16* __restrict__ Vt,
    const unsigned short* __restrict__ xdet) {
  __shared__ __align__(16) char smem[32768];  // A slots @0,8192 | B @16384,24576
  _Float16* Tb = (_Float16*)smem;             // V epilogue reuse (17.4KB)

  const int f = detect_bf16_flag(xdet);
  const bf16_t* A = f ? (const bf16_t*)xdet : xb;

  const int tid = threadIdx.x;
  const int n0 = blockIdx.x * 128, m0 = blockIdx.y * 128;
  const int r = tid >> 2, c8 = (tid & 3) << 3;
  const bf16_t* Ag = A + (size_t)(m0 + r) * 768 + c8;
  const bf16_t* Bg = Bm + (size_t)(n0 + r) * 768 + c8;
  const int wid = tid >> 6, lane = tid & 63;
  const int wm = (wid >> 1) << 6, wn = (wid & 1) << 6;
  const int lr = lane & 15, lk = (lane >> 4) << 3, g4 = (lane >> 4) << 2;

  f32x4 acc[4][4];
  const f32x4 z = {0.f, 0.f, 0.f, 0.f};
#pragma unroll
  for (int i = 0; i < 4; i++)
#pragma unroll
    for (int j = 0; j < 4; j++) acc[i][j] = z;

  {  // stage k0=0 -> slot 0
    bf16_t* A0 = (bf16_t*)smem;
    bf16_t* B0 = (bf16_t*)(smem + 16384);
    glds16(Ag, A0 + wid * 512);
    glds16(Ag + (size_t)64 * 768, A0 + 2048 + wid * 512);
    glds16(Bg, B0 + wid * 512);
    glds16(Bg + (size_t)64 * 768, B0 + 2048 + wid * 512);
  }
  __syncthreads();

  for (int s = 0; s < 24; s++) {
    if (s < 23) {  // prefetch s+1 into other slot (overlaps compute below)
      const int k0 = (s + 1) * 32;
      bf16_t* An = (bf16_t*)(smem + ((s + 1) & 1) * 8192);
      bf16_t* Bn = (bf16_t*)(smem + 16384 + ((s + 1) & 1) * 8192);
      glds16(Ag + k0, An + wid * 512);
      glds16(Ag + (size_t)64 * 768 + k0, An + 2048 + wid * 512);
      glds16(Bg + k0, Bn + wid * 512);
      glds16(Bg + (size_t)64 * 768 + k0, Bn + 2048 + wid * 512);
    }
    const bf16_t* As = (const bf16_t*)(smem + (s & 1) * 8192);
    const bf16_t* Bs = (const bf16_t*)(smem + 16384 + (s & 1) * 8192);
    bf16x8 af[4], bf_[4];
#pragma unroll
    for (int t = 0; t < 4; t++) af[t]  = *(const bf16x8*)&As[(wm + t * 16 + lr) * 32 + lk];
#pragma unroll
    for (int t = 0; t < 4; t++) bf_[t] = *(const bf16x8*)&Bs[(wn + t * 16 + lr) * 32 + lk];
#pragma unroll
    for (int i = 0; i < 4; i++)
#pragma unroll
      for (int j = 0; j < 4; j++)
        acc[i][j] = __builtin_amdgcn_mfma_f32_16x16x32_bf16(af[i], bf_[j], acc[i][j], 0, 0, 0);
    __syncthreads();  // joins waves + drains this iter's DMA (issued pre-compute)
  }

  if (n0 < 1536) {  // Q or K: scatter (16-lane runs contiguous over d)
    bf16_t* dst = (n0 < 768) ? Qd : Kd;
    const int nb = (n0 < 768) ? n0 : n0 - 768;
    const int bb = m0 >> 11;
#pragma unroll
    for (int i = 0; i < 4; i++)
#pragma unroll
      for (int j = 0; j < 4; j++) {
        const int rc = nb + wn + j * 16 + lr;
        const int hh = rc >> 6, dd = rc & 63;
        const size_t base = (((size_t)bb * 12 + hh) * 2048) * 64 + dd;
#pragma unroll
        for (int reg = 0; reg < 4; reg++) {
          const int s = (m0 & 2047) + wm + i * 16 + g4 + reg;
          dst[base + (size_t)s * 64] = (bf16_t)acc[i][j][reg];
        }
      }
  } else {  // V: LDS transpose -> coalesced V^T f16 writes
    const int bb = m0 >> 11;
#pragma unroll
    for (int half = 0; half < 2; half++) {
      if ((wid & 1) == half) {
#pragma unroll
        for (int j = 0; j < 4; j++) {
          const int d_l = j * 16 + lr;
#pragma unroll
          for (int i = 0; i < 4; i++)
#pragma unroll
            for (int reg = 0; reg < 4; reg++)
              Tb[d_l * 136 + wm + i * 16 + g4 + reg] = (_Float16)acc[i][j][reg];
        }
      }
      __syncthreads();
      const int row = tid >> 2, cc = (tid & 3) * 32;
      const int vcol = (n0 - 1536) + half * 64 + row;
      const int hh = vcol >> 6;  // d == row
      _Float16* dstv = Vt + (((size_t)bb * 12 + hh) * 64 + row) * 2048 + (m0 & 2047) + cc;
#pragma unroll
      for (int u = 0; u < 4; u++)
        *(uint4*)(dstv + u * 8) = *(const uint4*)&Tb[row * 136 + cc + u * 8];
      __syncthreads();
    }
  }
}

// ----------------------------------------------------------- flash attention
// R10 structure (verified 57.9us): 768 blocks x 320 thr, 4 consumers +
// producer, double-buffer, ones-MFMA row-sum.
__global__ __launch_bounds__(320, 4) void k_flash(
    const bf16_t* __restrict__ Qd, const bf16_t* __restrict__ Kd,
    const _Float16* __restrict__ Vt, const void* __restrict__ mask,
    const int* __restrict__ mflags, const unsigned short* __restrict__ xdet,
    bf16_t* __restrict__ attn) {
  __shared__ __align__(16) char sm[32768];  // buf p at p*16384: K 8KB | V 8KB

  const int tid = threadIdx.x, wid = tid >> 6, lane = tid & 63;
  const int lr = lane & 15, quad = lane >> 4, lk = quad << 3, g4 = quad << 2;

  const int lin = blockIdx.x;
  const int gx = lin & 7, ww = lin >> 3;
  const int hb = gx * 3 + (ww >> 5);
  const int h = hb % 12, bb = hb / 12;
  const int qt = ww & 31;

  const size_t bh = (size_t)bb * 12 + h;
  const char* Kh = (const char*)(Kd + bh * 2048 * 64);
  const char* Vh = (const char*)(Vt + bh * 64 * 2048);

  if (wid == 4) {
    const char* kS[8]; const char* vS[8];
#pragma unroll
    for (int u = 0; u < 8; u++) {
      const int R = (u >> 1) * 16 + lr;
      const int c = (u & 1) * 4 + quad;
      kS[u] = Kh + R * 128 + c * 16;
      const int u2 = u * 2 + (lane >> 5);
      const int dtv = u2 & 3, ctv = u2 >> 2, j2 = lane & 31;
      vS[u] = Vh + (size_t)(dtv * 16 + (j2 & 15)) * 4096 + ctv * 32 + (j2 >> 4) * 16;
    }
    uint4 kv[8], vv[8];
#pragma unroll
    for (int u = 0; u < 8; u++) kv[u] = *(const uint4*)(kS[u]);
#pragma unroll
    for (int u = 0; u < 8; u++) vv[u] = *(const uint4*)(vS[u]);
#pragma unroll
    for (int u = 0; u < 8; u++) *(uint4*)(sm + u * 1024 + lane * 16) = kv[u];
#pragma unroll
    for (int u = 0; u < 8; u++) *(uint4*)(sm + 8192 + u * 1024 + lane * 16) = vv[u];
    __syncthreads();
    for (int s = 0; s < 32; s++) {
      if (s < 31) {
        const int t = s + 1;
        char* buf = sm + (t & 1) * 16384;
#pragma unroll
        for (int u = 0; u < 8; u++) kv[u] = *(const uint4*)(kS[u] + (size_t)t * 8192);
#pragma unroll
        for (int u = 0; u < 8; u++) vv[u] = *(const uint4*)(vS[u] + (size_t)t * 128);
#pragma unroll
        for (int u = 0; u < 8; u++) *(uint4*)(buf + u * 1024 + lane * 16) = kv[u];
#pragma unroll
        for (int u = 0; u < 8; u++) *(uint4*)(buf + 8192 + u * 1024 + lane * 16) = vv[u];
      }
      __syncthreads();
    }
    return;
  }

  const bf16_t* Qh = Qd + bh * 2048 * 64;
  const int q0 = qt * 64 + wid * 16;
  const int mbf = detect_bf16_flag(xdet);
  const int* mfrow = mflags + (qt >> 1) * 16;
  int mbits = 0;
#pragma unroll
  for (int t = 0; t < 16; t++) mbits |= (mfrow[t] != 0) << t;

  const bf16x8 qf0 = *(const bf16x8*)&Qh[(size_t)(q0 + lr) * 64 + lk];
  const bf16x8 qf1 = *(const bf16x8*)&Qh[(size_t)(q0 + lr) * 64 + 32 + lk];

  f16x4 ones;
  ones[0] = (_Float16)1.f; ones[1] = (_Float16)1.f;
  ones[2] = (_Float16)1.f; ones[3] = (_Float16)1.f;

  const f32x4 z = {0.f, 0.f, 0.f, 0.f};
  f32x4 ot[4];
#pragma unroll
  for (int dt = 0; dt < 4; dt++) ot[dt] = z;
  float mrow = -1e30f, lrow = 0.f;

  __syncthreads();

  for (int s = 0; s < 32; s++) {
    const char* Kc = sm + (s & 1) * 16384;
    const char* Vc = Kc + 8192;

    f32x4 sv[4];
#pragma unroll
    for (int ct = 0; ct < 4; ct++) sv[ct] = z;
#pragma unroll
    for (int ct = 0; ct < 4; ct++) {
      bf16x8 kf0 = *(const bf16x8*)(Kc + ct * 2048 + lane * 16);
      bf16x8 kf1 = *(const bf16x8*)(Kc + ct * 2048 + 1024 + lane * 16);
      sv[ct] = __builtin_amdgcn_mfma_f32_16x16x32_bf16(kf0, qf0, sv[ct], 0, 0, 0);
      sv[ct] = __builtin_amdgcn_mfma_f32_16x16x32_bf16(kf1, qf1, sv[ct], 0, 0, 0);
    }

    if ((mbits >> (s >> 1)) & 1) {
#pragma unroll
      for (int ct = 0; ct < 4; ct++)
#pragma unroll
        for (int reg = 0; reg < 4; reg++) {
          size_t mi = (size_t)(q0 + lr) * 2048 + s * 64 + ct * 16 + g4 + reg;
          float mv = mbf ? bf2f(((const unsigned short*)mask)[mi])
                         : ((const float*)mask)[mi];
          sv[ct][reg] -= 8e9f * mv;
        }
    }

    float t = fmaxf(
        fmaxf(fmaxf(fmaxf(sv[0][0], sv[0][1]), fmaxf(sv[0][2], sv[0][3])),
              fmaxf(fmaxf(sv[1][0], sv[1][1]), fmaxf(sv[1][2], sv[1][3]))),
        fmaxf(fmaxf(fmaxf(sv[2][0], sv[2][1]), fmaxf(sv[2][2], sv[2][3])),
              fmaxf(fmaxf(sv[3][0], sv[3][1]), fmaxf(sv[3][2], sv[3][3]))));
    t = fmaxf(t, __shfl_xor(t, 16));
    t = fmaxf(t, __shfl_xor(t, 32));
    const float mnew = fmaxf(mrow, t);
    if (__ballot(mnew > mrow)) {
      const float alpha = fexp2((mrow - mnew) * SC2);
#pragma unroll
      for (int dt = 0; dt < 4; dt++)
#pragma unroll
        for (int reg = 0; reg < 4; reg++) ot[dt][reg] *= alpha;
      lrow *= alpha;
    }
    mrow = mnew;
    const float mS = mnew * SC2;

    f16x4 pb[4];
#pragma unroll
    for (int ct = 0; ct < 4; ct++) {
      float p0 = fexp2(fmaf(sv[ct][0], SC2, -mS));
      float p1 = fexp2(fmaf(sv[ct][1], SC2, -mS));
      float p2 = fexp2(fmaf(sv[ct][2], SC2, -mS));
      float p3 = fexp2(fmaf(sv[ct][3], SC2, -mS));
      union { hf2 h[2]; f16x4 v; } u;
      u.h[0] = __builtin_amdgcn_cvt_pkrtz(p0, p1);
      u.h[1] = __builtin_amdgcn_cvt_pkrtz(p2, p3);
      pb[ct] = u.v;
    }

    f32x4 asum = z;
#pragma unroll
    for (int ct = 0; ct < 4; ct++) {
      asum = __builtin_amdgcn_mfma_f32_16x16x16f16(ones, pb[ct], asum, 0, 0, 0);
#pragma unroll
      for (int dt = 0; dt < 4; dt++) {
        f16x4 va = *(const f16x4*)(Vc + (ct * 4 + dt) * 512 +
                                   (quad >> 1) * 256 + lr * 16 + (quad & 1) * 8);
        ot[dt] = __builtin_amdgcn_mfma_f32_16x16x16f16(va, pb[ct], ot[dt], 0, 0, 0);
      }
    }
    lrow += asum[0];
    __syncthreads();
  }

  const float inv = 1.0f / lrow;
  bf16_t* arow = attn + ((size_t)bb * 2048 + q0 + lr) * 768 + h * 64 + g4;
#pragma unroll
  for (int dt = 0; dt < 4; dt++) {
    bf16x4 v;
#pragma unroll
    for (int reg = 0; reg < 4; reg++) v[reg] = (bf16_t)(ot[dt][reg] * inv);
    *(bf16x4*)(arow + dt * 16) = v;
  }
}

// -------------------------------------------------- output GEMM (attn @ Wo^T)
// 64x64 tiles -> 768 blocks (3/CU), BK=64 double-buffered with
// prefetch-before-compute (two 32-k sub-tiles per slot).
__global__ __launch_bounds__(256, 3) void k_gemm2(
    const bf16_t* __restrict__ A, const bf16_t* __restrict__ Bm,
    const void* __restrict__ bo, const unsigned short* __restrict__ xdet,
    float* __restrict__ outF, unsigned short* __restrict__ outH) {
  __shared__ __align__(16) char smem[32768];  // A slots @0,8192 | B @16384,24576

  const int tid = threadIdx.x, wid = tid >> 6, lane = tid & 63;
  const int n0 = blockIdx.x * 64, m0 = blockIdx.y * 64;
  const int wm = (wid >> 1) << 5, wn = (wid & 1) << 5;
  const int lr = lane & 15, lk = (lane >> 4) << 3, g4 = (lane >> 4) << 2;
  const bf16_t* Ag = A + (size_t)(m0 + (tid >> 2)) * 768 + ((tid & 3) << 3);
  const bf16_t* Bg = Bm + (size_t)(n0 + (tid >> 2)) * 768 + ((tid & 3) << 3);

  f32x4 acc[2][2];
  const f32x4 z = {0.f, 0.f, 0.f, 0.f};
#pragma unroll
  for (int i = 0; i < 2; i++)
#pragma unroll
    for (int j = 0; j < 2; j++) acc[i][j] = z;

  {  // stage k0=0 -> slot 0 (two 32-k halves per operand)
    bf16_t* A0 = (bf16_t*)smem;
    bf16_t* B0 = (bf16_t*)(smem + 16384);
    glds16(Ag, A0 + wid * 512);
    glds16(Ag + 32, A0 + 2048 + wid * 512);
    glds16(Bg, B0 + wid * 512);
    glds16(Bg + 32, B0 + 2048 + wid * 512);
  }
  __syncthreads();

  for (int s = 0; s < 12; s++) {
    if (s < 11) {  // prefetch s+1 into other slot
      const int k0 = (s + 1) * 64;
      bf16_t* An = (bf16_t*)(smem + ((s + 1) & 1) * 8192);
      bf16_t* Bn = (bf16_t*)(smem + 16384 + ((s + 1) & 1) * 8192);
      glds16(Ag + k0, An + wid * 512);
      glds16(Ag + k0 + 32, An + 2048 + wid * 512);
      glds16(Bg + k0, Bn + wid * 512);
      glds16(Bg + k0 + 32, Bn + 2048 + wid * 512);
    }
#pragma unroll
    for (int kc = 0; kc < 2; kc++) {
      const bf16_t* As = (const bf16_t*)(smem + (s & 1) * 8192) + kc * 2048;
      const bf16_t* Bs = (const bf16_t*)(smem + 16384 + (s & 1) * 8192) + kc * 2048;
      bf16x8 af[2], bf_[2];
#pragma unroll
      for (int i = 0; i < 2; i++) af[i]  = *(const bf16x8*)&As[(wm + i * 16 + lr) * 32 + lk];
#pragma unroll
      for (int j = 0; j < 2; j++) bf_[j] = *(const bf16x8*)&Bs[(wn + j * 16 + lr) * 32 + lk];
#pragma unroll
      for (int i = 0; i < 2; i++)
#pragma unroll
        for (int j = 0; j < 2; j++)
          acc[i][j] = __builtin_amdgcn_mfma_f32_16x16x32_bf16(af[i], bf_[j], acc[i][j], 0, 0, 0);
    }
    __syncthreads();
  }

  const int obf = detect_bf16_flag(xdet);
#pragma unroll
  for (int i = 0; i < 2; i++)
#pragma unroll
    for (int j = 0; j < 2; j++) {
      const int nn = n0 + wn + j * 16 + lr;
      const float bv = obf ? bf2f(((const unsigned short*)bo)[nn])
                           : ((const float*)bo)[nn];
#pragma unroll
      for (int reg = 0; reg < 4; reg++) {
        const int m = m0 + wm + i * 16 + g4 + reg;
        const float v = acc[i][j][reg] + bv;
        if (obf) outH[(size_t)m * 768 + nn] = __builtin_bit_cast(unsigned short, (bf16_t)v);
        else     outF[(size_t)m * 768 + nn] = v;
      }
    }
}

// -------------------------------------------------------------------- launch
extern "C" void kernel_launch(void* const* d_in, const int* in_sizes, int n_in,
                              void* d_out, int out_size, void* d_ws, size_t ws_size,
                              hipStream_t stream) {
  (void)in_sizes; (void)n_in; (void)out_size; (void)ws_size;
  const void* x    = d_in[0];
  const void* mask = d_in[1];
  const void* Wq   = d_in[2];
  const void* Wk   = d_in[3];
  const void* Wv   = d_in[4];
  const void* Wo   = d_in[5];
  const void* bo   = d_in[6];

  char* w = (char*)d_ws;
  size_t off = 0;
  auto take = [&](size_t b) -> void* {
    void* p = w + off;
    off = (off + b + 255) & ~(size_t)255;
    return p;
  };
  int*      mflags = (int*)take(256 * 4);
  bf16_t*   wqkvT  = (bf16_t*)take((size_t)2304 * 768 * 2);
  bf16_t*   woT    = (bf16_t*)take((size_t)768 * 768 * 2);
  bf16_t*   xb     = (bf16_t*)take((size_t)4096 * 768 * 2);
  bf16_t*   Qd     = (bf16_t*)take((size_t)3145728 * 2);
  bf16_t*   Kd     = (bf16_t*)take((size_t)3145728 * 2);
  _Float16* Vt     = (_Float16*)take((size_t)3145728 * 2);
  bf16_t*   attn   = xb;  // xb dead after QKV GEMM (flash output reuses it)

  k_prep<<<4096, 256, 0, stream>>>(x, mask, Wq, Wk, Wv, Wo, xb, wqkvT, woT, mflags);
  k_gemmQKV<<<dim3(18, 32), 256, 0, stream>>>(xb, wqkvT, Qd, Kd, Vt,
                                              (const unsigned short*)x);
  k_flash<<<768, 320, 0, stream>>>(Qd, Kd, Vt, mask, mflags,
                                   (const unsigned short*)x, attn);
  k_gemm2<<<dim3(12, 64), 256, 0, stream>>>(attn, woT, bo, (const unsigned short*)x,
                                            (float*)d_out, (unsigned short*)d_out);
}